// Round 1
// baseline (159.144 us; speedup 1.0000x reference)
//
#include <hip/hip_runtime.h>

// Problem constants
#define BB   32
#define CC   64
#define MM   8
#define NSP  16384            // H*W = 128*128
#define CNTF 524288.0f        // B*N, BN statistics count

// Workspace layout (float offsets)
#define OFF_FXP   0ll
#define OFF_GXP   (OFF_FXP + (long long)BB*MM*NSP)      //  4,194,304
#define OFF_HX    (OFF_GXP + (long long)BB*MM*NSP)      //  8,388,608
#define OFF_WT    (OFF_HX  + (long long)BB*MM*NSP)      // 12,582,912  [64][24]
#define OFF_STATS (OFF_WT + 64*24)                      // 12,584,448  [32]: fsum8 fsq8 gsum8 gsq8
#define OFF_WSA   (OFF_STATS + 32)                      // 12,584,480  [B][3][64]: Wsf Wsg Cross
#define OFF_VFN   (OFF_WSA + (long long)BB*192)         // 12,590,624  [B][8]   v_f / ||fx v_f||
#define OFF_W2    (OFF_VFN + (long long)BB*MM)          // 12,590,880  [B][64]  v_w @ coef

// ---------------------------------------------------------------------------
// K0: pack f/g/h weights [M=8][C=64] -> wT[c][24] (f0..7, g0..7, h0..7)
__global__ void k_pack(const float* __restrict__ fw, const float* __restrict__ gw,
                       const float* __restrict__ hw, float* __restrict__ ws) {
    int i = blockIdx.x * 256 + threadIdx.x;
    if (i < 1536) {
        int c = i / 24, k = i % 24;
        float v = (k < 8) ? fw[k * 64 + c]
                : (k < 16) ? gw[(k - 8) * 64 + c]
                           : hw[(k - 16) * 64 + c];
        ws[OFF_WT + i] = v;
    }
}

// ---------------------------------------------------------------------------
// K1: one pass over x -> fxp/gxp/hx in [B][M][N] layout (pre-BN conv outputs)
#define FMA4(A0, A1, W, XV)                                        \
    (A0)[0] = fmaf((XV).x, (W).x, (A0)[0]); (A1)[0] = fmaf((XV).y, (W).x, (A1)[0]); \
    (A0)[1] = fmaf((XV).x, (W).y, (A0)[1]); (A1)[1] = fmaf((XV).y, (W).y, (A1)[1]); \
    (A0)[2] = fmaf((XV).x, (W).z, (A0)[2]); (A1)[2] = fmaf((XV).y, (W).z, (A1)[2]); \
    (A0)[3] = fmaf((XV).x, (W).w, (A0)[3]); (A1)[3] = fmaf((XV).y, (W).w, (A1)[3]);

__global__ __launch_bounds__(256) void k_conv(const float* __restrict__ x,
        const float* __restrict__ fb, const float* __restrict__ gb,
        const float* __restrict__ hb, float* __restrict__ ws) {
    __shared__ float wt[1536];
    for (int i = threadIdx.x; i < 1536; i += 256) wt[i] = ws[OFF_WT + i];
    __syncthreads();

    int g  = blockIdx.x * 256 + threadIdx.x;   // pair index (2 n per thread)
    int b  = g >> 13;                          // 8192 pairs per batch
    int n0 = (g & 8191) * 2;

    const float* xp = x + (size_t)b * CC * NSP + n0;

    float af0[8], af1[8], ag0[8], ag1[8], ah0[8], ah1[8];
#pragma unroll
    for (int m = 0; m < 8; ++m) {
        af0[m] = af1[m] = fb[m];
        ag0[m] = ag1[m] = gb[m];
        ah0[m] = ah1[m] = hb[m];
    }

#pragma unroll 8
    for (int c = 0; c < 64; ++c) {
        float2 xv = *(const float2*)(xp + (size_t)c * NSP);
        const float4* w4 = (const float4*)(&wt[c * 24]);
        float4 w0 = w4[0], w1 = w4[1], w2_ = w4[2], w3 = w4[3], w4_ = w4[4], w5 = w4[5];
        FMA4(af0,     af1,     w0,  xv);
        FMA4(af0 + 4, af1 + 4, w1,  xv);
        FMA4(ag0,     ag1,     w2_, xv);
        FMA4(ag0 + 4, ag1 + 4, w3,  xv);
        FMA4(ah0,     ah1,     w4_, xv);
        FMA4(ah0 + 4, ah1 + 4, w5,  xv);
    }

    size_t base = (size_t)b * MM * NSP + n0;
#pragma unroll
    for (int m = 0; m < 8; ++m) {
        *(float2*)(ws + OFF_FXP + base + (size_t)m * NSP) = make_float2(af0[m], af1[m]);
        *(float2*)(ws + OFF_GXP + base + (size_t)m * NSP) = make_float2(ag0[m], ag1[m]);
        *(float2*)(ws + OFF_HX  + base + (size_t)m * NSP) = make_float2(ah0[m], ah1[m]);
    }
}

// ---------------------------------------------------------------------------
// K2: BN stats (sum, sumsq) per channel for f and g streams.
// grid 512: s=bid>>8 (0=f,1=g), m=(bid>>5)&7, slice=bid&31 (32 slices of B*N)
__global__ __launch_bounds__(256) void k_stats(float* __restrict__ ws) {
    int bid = blockIdx.x;
    int s = bid >> 8, m = (bid >> 5) & 7, slice = bid & 31;
    const float4* src = (const float4*)(ws + (s ? OFF_GXP : OFF_FXP));

    float sum = 0.f, sq = 0.f;
#pragma unroll 4
    for (int i = 0; i < 16; ++i) {
        int g4 = slice * 4096 + i * 256 + threadIdx.x;   // float4 index over (b,n)
        int b = g4 >> 12, n4 = g4 & 4095;                // 4096 float4 per (b,m) slice
        float4 v = src[(size_t)(b * 8 + m) * 4096 + n4];
        sum += v.x + v.y + v.z + v.w;
        sq  += v.x * v.x + v.y * v.y + v.z * v.z + v.w * v.w;
    }
#pragma unroll
    for (int o = 1; o < 64; o <<= 1) {
        sum += __shfl_xor(sum, o);
        sq  += __shfl_xor(sq, o);
    }
    __shared__ float r[8];
    int wid = threadIdx.x >> 6, lane = threadIdx.x & 63;
    if (lane == 0) { r[wid] = sum; r[4 + wid] = sq; }
    __syncthreads();
    if (threadIdx.x == 0) {
        float ts = r[0] + r[1] + r[2] + r[3];
        float tq = r[4] + r[5] + r[6] + r[7];
        atomicAdd(ws + OFF_STATS + s * 16 + m, ts);
        atomicAdd(ws + OFF_STATS + s * 16 + 8 + m, tq);
    }
}

// ---------------------------------------------------------------------------
// K3: per-batch 8x8 Gram matrices. which: 0=Wsf(fx,fx) 1=Wsg(gx,gx) 2=Cross(hx,gx)
// grid 768 = 32 b * 3 which * 8 chunks
__global__ __launch_bounds__(256) void k_gram(
        const float* __restrict__ fgam, const float* __restrict__ fbet,
        const float* __restrict__ ggam, const float* __restrict__ gbet,
        float* __restrict__ ws) {
    int bid = blockIdx.x;
    int chunk = bid & 7, which = (bid >> 3) % 3, b = bid / 24;

    const float* st  = ws + OFF_STATS + (which == 0 ? 0 : 16);
    const float* gam = (which == 0) ? fgam : ggam;
    const float* bet = (which == 0) ? fbet : gbet;
    const float inv = 1.f / CNTF;
    float a[8], ccf[8];
#pragma unroll
    for (int m = 0; m < 8; ++m) {
        float mean = st[m] * inv;
        float var  = st[8 + m] * inv - mean * mean;
        float sc   = gam[m] / sqrtf(var + 1e-5f);
        a[m] = sc; ccf[m] = bet[m] - mean * sc;
    }

    const float* src  = ws + (which == 0 ? OFF_FXP : OFF_GXP) + (size_t)b * MM * NSP;
    const float* hsrc = ws + OFF_HX + (size_t)b * MM * NSP;

    float acc[64];
#pragma unroll
    for (int j = 0; j < 64; ++j) acc[j] = 0.f;

    for (int i = 0; i < 8; ++i) {
        int n = chunk * 2048 + i * 256 + threadIdx.x;
        float v[8], h[8];
#pragma unroll
        for (int m = 0; m < 8; ++m) {
            float t = fmaf(a[m], src[(size_t)m * NSP + n], ccf[m]);
            v[m] = t > 0.f ? t : 0.f;
        }
        if (which == 2) {
#pragma unroll
            for (int m = 0; m < 8; ++m) h[m] = hsrc[(size_t)m * NSP + n];
        } else {
#pragma unroll
            for (int m = 0; m < 8; ++m) h[m] = v[m];
        }
#pragma unroll
        for (int m2 = 0; m2 < 8; ++m2)
#pragma unroll
            for (int k = 0; k < 8; ++k)
                acc[m2 * 8 + k] = fmaf(h[m2], v[k], acc[m2 * 8 + k]);
    }

    // reduce-scatter butterfly across the wave: all register indices static,
    // lane l ends with the total of acc[bitrev6(l)] in acc[0].
    int lane = threadIdx.x & 63;
#pragma unroll
    for (int s2 = 0; s2 < 6; ++s2) {
        int half = 32 >> s2;
        int up = (lane >> s2) & 1;
#pragma unroll
        for (int j = 0; j < 32; ++j) {
            if (j >= half) break;
            float send = up ? acc[j] : acc[j + half];
            float recv = __shfl_xor(send, 1 << s2);
            float keep = up ? acc[j + half] : acc[j];
            acc[j] = keep + recv;
        }
    }
    __shared__ float sacc[64];
    if (threadIdx.x < 64) sacc[threadIdx.x] = 0.f;
    __syncthreads();
    int rev = __brev((unsigned)lane) >> 26;     // runtime LDS address is fine
    atomicAdd(&sacc[rev], acc[0]);
    __syncthreads();
    if (threadIdx.x < 64)
        atomicAdd(ws + OFF_WSA + b * 192 + which * 64 + threadIdx.x, sacc[threadIdx.x]);
}

// ---------------------------------------------------------------------------
// K4: power iteration (30 iters, 8x8) for f and g; emit vfn = v_f/||fx v_f||
// and w2[b][c] = sum_m v_w[c,m] * coef[m], coef = Cross v_g / ||gx v_g||.
// grid 32 blocks, 64 threads (one wave). lanes 0-7: f, lanes 8-15: g.
__global__ void k_power(const float* __restrict__ vw,
                        const float* __restrict__ v0f, const float* __restrict__ v0g,
                        float* __restrict__ ws) {
    int b = blockIdx.x;
    int lane = threadIdx.x;
    __shared__ float coef[8];
    int grp = lane >> 3, m = lane & 7;
    if (grp < 2) {
        const float* Ws = ws + OFF_WSA + b * 192 + grp * 64;
        float row[8];
#pragma unroll
        for (int k = 0; k < 8; ++k) row[k] = Ws[m * 8 + k];
        float v = (grp == 0 ? v0f : v0g)[b * 8 + m];
        for (int it = 0; it < 30; ++it) {
            float t = 0.f;
#pragma unroll
            for (int k = 0; k < 8; ++k) t = fmaf(row[k], __shfl(v, k, 8), t);
            float s = t * t;
            s += __shfl_xor(s, 1, 8); s += __shfl_xor(s, 2, 8); s += __shfl_xor(s, 4, 8);
            v = t / sqrtf(s);
        }
        // norm^2 = v^T Ws v  (== ||W v||^2, no pass over N needed)
        float t = 0.f;
#pragma unroll
        for (int k = 0; k < 8; ++k) t = fmaf(row[k], __shfl(v, k, 8), t);
        float s = v * t;
        s += __shfl_xor(s, 1, 8); s += __shfl_xor(s, 2, 8); s += __shfl_xor(s, 4, 8);
        float invn = 1.f / sqrtf(s);
        if (grp == 0) {
            ws[OFF_VFN + b * 8 + m] = v * invn;
        } else {
            const float* Cr = ws + OFF_WSA + b * 192 + 128;
            float cf = 0.f;
#pragma unroll
            for (int k = 0; k < 8; ++k) cf = fmaf(Cr[m * 8 + k], __shfl(v, k, 8), cf);
            coef[m] = cf * invn;
        }
    }
    __syncthreads();
    float acc = 0.f;
#pragma unroll
    for (int k = 0; k < 8; ++k) acc = fmaf(vw[lane * 8 + k], coef[k], acc);
    ws[OFF_W2 + b * 64 + lane] = acc;
}

// ---------------------------------------------------------------------------
// K5: out[b,c,n] = uf[b,n]*w2[b,c] + v_b[c] + x[b,c,n]
// grid 512 = 32 b * 16 tiles of 1024 n; threads own 4 consecutive n (float4).
__global__ __launch_bounds__(256) void k_out(const float* __restrict__ x,
        const float* __restrict__ fgam, const float* __restrict__ fbet,
        const float* __restrict__ vb, const float* __restrict__ ws,
        float* __restrict__ out) {
    int bid = blockIdx.x;
    int b = bid >> 4, tile = bid & 15;
    int n0 = tile * 1024 + threadIdx.x * 4;

    const float inv = 1.f / CNTF;
    const float* st  = ws + OFF_STATS;
    const float* vfn = ws + OFF_VFN + b * 8;

    float uf0 = 0.f, uf1 = 0.f, uf2 = 0.f, uf3 = 0.f;
#pragma unroll
    for (int m = 0; m < 8; ++m) {
        float mean = st[m] * inv;
        float var  = st[8 + m] * inv - mean * mean;
        float a    = fgam[m] / sqrtf(var + 1e-5f);
        float cc   = fbet[m] - mean * a;
        float vf   = vfn[m];
        float4 fv  = *(const float4*)(ws + OFF_FXP + (size_t)(b * 8 + m) * NSP + n0);
        float t0 = fmaf(a, fv.x, cc); t0 = t0 > 0.f ? t0 : 0.f; uf0 = fmaf(vf, t0, uf0);
        float t1 = fmaf(a, fv.y, cc); t1 = t1 > 0.f ? t1 : 0.f; uf1 = fmaf(vf, t1, uf1);
        float t2 = fmaf(a, fv.z, cc); t2 = t2 > 0.f ? t2 : 0.f; uf2 = fmaf(vf, t2, uf2);
        float t3 = fmaf(a, fv.w, cc); t3 = t3 > 0.f ? t3 : 0.f; uf3 = fmaf(vf, t3, uf3);
    }

    const float* xp  = x   + (size_t)b * CC * NSP + n0;
    float*       op  = out + (size_t)b * CC * NSP + n0;
    const float* w2p = ws + OFF_W2 + b * 64;
#pragma unroll 8
    for (int c = 0; c < 64; ++c) {
        float w2c = w2p[c];
        float bc  = vb[c];
        float4 xv = *(const float4*)(xp + (size_t)c * NSP);
        float4 ov;
        ov.x = fmaf(uf0, w2c, xv.x + bc);
        ov.y = fmaf(uf1, w2c, xv.y + bc);
        ov.z = fmaf(uf2, w2c, xv.z + bc);
        ov.w = fmaf(uf3, w2c, xv.w + bc);
        *(float4*)(op + (size_t)c * NSP) = ov;
    }
}

// ---------------------------------------------------------------------------
extern "C" void kernel_launch(void* const* d_in, const int* in_sizes, int n_in,
                              void* d_out, int out_size, void* d_ws, size_t ws_size,
                              hipStream_t stream) {
    const float* x    = (const float*)d_in[0];
    const float* f_w  = (const float*)d_in[1];
    const float* f_b  = (const float*)d_in[2];
    const float* f_g  = (const float*)d_in[3];
    const float* f_be = (const float*)d_in[4];
    const float* g_w  = (const float*)d_in[5];
    const float* g_b  = (const float*)d_in[6];
    const float* g_g  = (const float*)d_in[7];
    const float* g_be = (const float*)d_in[8];
    const float* h_w  = (const float*)d_in[9];
    const float* h_b  = (const float*)d_in[10];
    const float* v_w  = (const float*)d_in[11];
    const float* v_b  = (const float*)d_in[12];
    const float* v0f  = (const float*)d_in[13];
    const float* v0g  = (const float*)d_in[14];
    float* ws  = (float*)d_ws;
    float* out = (float*)d_out;

    // zero the atomic accumulators (stats + Gram), contiguous region
    hipMemsetAsync(ws + OFF_STATS, 0, (32 + BB * 192) * sizeof(float), stream);

    k_pack <<<6,    256, 0, stream>>>(f_w, g_w, h_w, ws);
    k_conv <<<1024, 256, 0, stream>>>(x, f_b, g_b, h_b, ws);
    k_stats<<<512,  256, 0, stream>>>(ws);
    k_gram <<<768,  256, 0, stream>>>(f_g, f_be, g_g, g_be, ws);
    k_power<<<32,   64,  0, stream>>>(v_w, v0f, v0g, ws);
    k_out  <<<512,  256, 0, stream>>>(x, f_g, f_be, v_b, ws, out);
}

// Round 3
// 129.526 us; speedup vs baseline: 1.2287x; 1.2287x over previous
//
#include <hip/hip_runtime.h>

// Problem constants
#define BB   32
#define CC   64
#define MM   8
#define NSP  16384            // H*W = 128*128
#define CNTF 524288.0f        // B*N, BN statistics count

typedef float f32x4 __attribute__((ext_vector_type(4)));

// Workspace layout (float offsets)
#define OFF_FXP   0ll
#define OFF_GXP   (OFF_FXP + (long long)BB*MM*NSP)      //  4,194,304
#define OFF_HX    (OFF_GXP + (long long)BB*MM*NSP)      //  8,388,608
#define OFF_STATS (OFF_HX  + (long long)BB*MM*NSP)      // 12,582,912  [32]: fsum8 fsq8 gsum8 gsq8
#define OFF_WSA   (OFF_STATS + 32)                      // [B][3][64]: Wsf Wsg Cross (contiguous with STATS)

#define AXPY(A, WS, XV) \
    (A).x = fmaf((WS), (XV).x, (A).x); (A).y = fmaf((WS), (XV).y, (A).y); \
    (A).z = fmaf((WS), (XV).z, (A).z); (A).w = fmaf((WS), (XV).w, (A).w);

// ---------------------------------------------------------------------------
// K1: fused pack + conv + BN-stats.
// One pass over x -> fxp/gxp/hx in [B][M][N] layout (pre-BN conv outputs),
// plus per-channel sum/sumsq for the f and g streams via register reduction.
// grid 512 x 256; each thread owns 4 consecutive n (float4).
__global__ __launch_bounds__(256) void k_conv(const float* __restrict__ x,
        const float* __restrict__ fw, const float* __restrict__ gw,
        const float* __restrict__ hw,
        const float* __restrict__ fb, const float* __restrict__ gb,
        const float* __restrict__ hb, float* __restrict__ ws) {
    __shared__ float wt[1536];          // [c][24]: f0..7 g0..7 h0..7
    __shared__ float sred[4][32];
    for (int i = threadIdx.x; i < 1536; i += 256) {
        int c = i / 24, k = i % 24;
        float v = (k < 8) ? fw[k * 64 + c]
                : (k < 16) ? gw[(k - 8) * 64 + c]
                           : hw[(k - 16) * 64 + c];
        wt[i] = v;
    }
    __syncthreads();

    int g  = blockIdx.x * 256 + threadIdx.x;   // quad index (4 n per thread)
    int b  = g >> 12;                          // 4096 quads per batch
    int n0 = (g & 4095) * 4;

    const float* xp = x + (size_t)b * CC * NSP + n0;

    float4 af[8], ag[8], ah[8];
#pragma unroll
    for (int m = 0; m < 8; ++m) {
        float bf = fb[m], bg = gb[m], bh = hb[m];
        af[m] = make_float4(bf, bf, bf, bf);
        ag[m] = make_float4(bg, bg, bg, bg);
        ah[m] = make_float4(bh, bh, bh, bh);
    }

#pragma unroll 8
    for (int c = 0; c < 64; ++c) {
        float4 xv = *(const float4*)(xp + (size_t)c * NSP);
        const float4* w4 = (const float4*)(&wt[c * 24]);
        float4 wf0 = w4[0], wf1 = w4[1], wg0 = w4[2], wg1 = w4[3], wh0 = w4[4], wh1 = w4[5];
        AXPY(af[0], wf0.x, xv); AXPY(af[1], wf0.y, xv); AXPY(af[2], wf0.z, xv); AXPY(af[3], wf0.w, xv);
        AXPY(af[4], wf1.x, xv); AXPY(af[5], wf1.y, xv); AXPY(af[6], wf1.z, xv); AXPY(af[7], wf1.w, xv);
        AXPY(ag[0], wg0.x, xv); AXPY(ag[1], wg0.y, xv); AXPY(ag[2], wg0.z, xv); AXPY(ag[3], wg0.w, xv);
        AXPY(ag[4], wg1.x, xv); AXPY(ag[5], wg1.y, xv); AXPY(ag[6], wg1.z, xv); AXPY(ag[7], wg1.w, xv);
        AXPY(ah[0], wh0.x, xv); AXPY(ah[1], wh0.y, xv); AXPY(ah[2], wh0.z, xv); AXPY(ah[3], wh0.w, xv);
        AXPY(ah[4], wh1.x, xv); AXPY(ah[5], wh1.y, xv); AXPY(ah[6], wh1.z, xv); AXPY(ah[7], wh1.w, xv);
    }

    size_t base = (size_t)b * MM * NSP + n0;
#pragma unroll
    for (int m = 0; m < 8; ++m) {
        *(float4*)(ws + OFF_FXP + base + (size_t)m * NSP) = af[m];
        *(float4*)(ws + OFF_GXP + base + (size_t)m * NSP) = ag[m];
        *(float4*)(ws + OFF_HX  + base + (size_t)m * NSP) = ah[m];
    }

    // BN stats from registers: per-channel sum & sumsq for f and g
    int wid = threadIdx.x >> 6, lane = threadIdx.x & 63;
#pragma unroll
    for (int m = 0; m < 8; ++m) {
        float fs = af[m].x + af[m].y + af[m].z + af[m].w;
        float fq = af[m].x * af[m].x + af[m].y * af[m].y + af[m].z * af[m].z + af[m].w * af[m].w;
        float gs = ag[m].x + ag[m].y + ag[m].z + ag[m].w;
        float gq = ag[m].x * ag[m].x + ag[m].y * ag[m].y + ag[m].z * ag[m].z + ag[m].w * ag[m].w;
#pragma unroll
        for (int o = 1; o < 64; o <<= 1) {
            fs += __shfl_xor(fs, o); fq += __shfl_xor(fq, o);
            gs += __shfl_xor(gs, o); gq += __shfl_xor(gq, o);
        }
        if (lane == 0) {
            sred[wid][m] = fs; sred[wid][8 + m] = fq;
            sred[wid][16 + m] = gs; sred[wid][24 + m] = gq;
        }
    }
    __syncthreads();
    if (threadIdx.x < 32) {
        float t = sred[0][threadIdx.x] + sred[1][threadIdx.x]
                + sred[2][threadIdx.x] + sred[3][threadIdx.x];
        atomicAdd(ws + OFF_STATS + threadIdx.x, t);
    }
}

// ---------------------------------------------------------------------------
// K2: per-batch 8x8 Gram matrices. which: 0=Wsf(fx,fx) 1=Wsg(gx,gx) 2=Cross(hx,gx)
// grid 768 = 32 b * 3 which * 8 chunks; float4 reads (2 per thread per m)
__global__ __launch_bounds__(256) void k_gram(
        const float* __restrict__ fgam, const float* __restrict__ fbet,
        const float* __restrict__ ggam, const float* __restrict__ gbet,
        float* __restrict__ ws) {
    int bid = blockIdx.x;
    int chunk = bid & 7, which = (bid >> 3) % 3, b = bid / 24;

    const float* st  = ws + OFF_STATS + (which == 0 ? 0 : 16);
    const float* gam = (which == 0) ? fgam : ggam;
    const float* bet = (which == 0) ? fbet : gbet;
    const float inv = 1.f / CNTF;
    float a[8], ccf[8];
#pragma unroll
    for (int m = 0; m < 8; ++m) {
        float mean = st[m] * inv;
        float var  = st[8 + m] * inv - mean * mean;
        float sc   = gam[m] / sqrtf(var + 1e-5f);
        a[m] = sc; ccf[m] = bet[m] - mean * sc;
    }

    const float* src  = ws + (which == 0 ? OFF_FXP : OFF_GXP) + (size_t)b * MM * NSP;
    const float* hsrc = ws + OFF_HX + (size_t)b * MM * NSP;

    float acc[64];
#pragma unroll
    for (int j = 0; j < 64; ++j) acc[j] = 0.f;

#pragma unroll
    for (int i = 0; i < 2; ++i) {
        int n = (chunk * 512 + i * 256 + threadIdx.x) * 4;
        float4 vv[8], hh[8];
#pragma unroll
        for (int m = 0; m < 8; ++m) {
            float4 t = *(const float4*)(src + (size_t)m * NSP + n);
            t.x = fmaf(a[m], t.x, ccf[m]); t.x = t.x > 0.f ? t.x : 0.f;
            t.y = fmaf(a[m], t.y, ccf[m]); t.y = t.y > 0.f ? t.y : 0.f;
            t.z = fmaf(a[m], t.z, ccf[m]); t.z = t.z > 0.f ? t.z : 0.f;
            t.w = fmaf(a[m], t.w, ccf[m]); t.w = t.w > 0.f ? t.w : 0.f;
            vv[m] = t;
        }
        if (which == 2) {
#pragma unroll
            for (int m = 0; m < 8; ++m) hh[m] = *(const float4*)(hsrc + (size_t)m * NSP + n);
        } else {
#pragma unroll
            for (int m = 0; m < 8; ++m) hh[m] = vv[m];
        }
#pragma unroll
        for (int m2 = 0; m2 < 8; ++m2)
#pragma unroll
            for (int k = 0; k < 8; ++k) {
                float t = acc[m2 * 8 + k];
                t = fmaf(hh[m2].x, vv[k].x, t);
                t = fmaf(hh[m2].y, vv[k].y, t);
                t = fmaf(hh[m2].z, vv[k].z, t);
                t = fmaf(hh[m2].w, vv[k].w, t);
                acc[m2 * 8 + k] = t;
            }
    }

    // reduce-scatter butterfly across the wave: all register indices static,
    // lane l ends with the total of acc[bitrev6(l)] in acc[0].
    int lane = threadIdx.x & 63;
#pragma unroll
    for (int s2 = 0; s2 < 6; ++s2) {
        int half = 32 >> s2;
        int up = (lane >> s2) & 1;
#pragma unroll
        for (int j = 0; j < 32; ++j) {
            if (j >= half) break;
            float send = up ? acc[j] : acc[j + half];
            float recv = __shfl_xor(send, 1 << s2);
            float keep = up ? acc[j + half] : acc[j];
            acc[j] = keep + recv;
        }
    }
    __shared__ float sacc[64];
    if (threadIdx.x < 64) sacc[threadIdx.x] = 0.f;
    __syncthreads();
    int rev = __brev((unsigned)lane) >> 26;
    atomicAdd(&sacc[rev], acc[0]);
    __syncthreads();
    if (threadIdx.x < 64)
        atomicAdd(ws + OFF_WSA + b * 192 + which * 64 + threadIdx.x, sacc[threadIdx.x]);
}

// ---------------------------------------------------------------------------
// K3: fused power-iteration + rank-1 epilogue + residual.
// Lanes 0-15 run the 30-iter 8x8 power iteration (f in lanes 0-7, g in 8-15),
// then w2[c] = v_w @ coef in LDS, then out[b,c,n] = uf[n]*w2[c] + v_b[c] + x.
// grid 512 = 32 b * 16 tiles of 1024 n.
__global__ __launch_bounds__(256) void k_out(const float* __restrict__ x,
        const float* __restrict__ fgam, const float* __restrict__ fbet,
        const float* __restrict__ vw, const float* __restrict__ vb,
        const float* __restrict__ v0f, const float* __restrict__ v0g,
        const float* __restrict__ ws, float* __restrict__ out) {
    int bid = blockIdx.x;
    int b = bid >> 4, tile = bid & 15;
    __shared__ float s_vfn[8], s_coef[8], s_w2[64];

    if (threadIdx.x < 16) {
        int grp = threadIdx.x >> 3, m = threadIdx.x & 7;
        const float* Ws = ws + OFF_WSA + b * 192 + grp * 64;
        float row[8];
#pragma unroll
        for (int k = 0; k < 8; ++k) row[k] = Ws[m * 8 + k];
        float v = (grp == 0 ? v0f : v0g)[b * 8 + m];
        for (int it = 0; it < 30; ++it) {
            float t = 0.f;
#pragma unroll
            for (int k = 0; k < 8; ++k) t = fmaf(row[k], __shfl(v, k, 8), t);
            float s = t * t;
            s += __shfl_xor(s, 1, 8); s += __shfl_xor(s, 2, 8); s += __shfl_xor(s, 4, 8);
            v = t / sqrtf(s);
        }
        // ||W v||^2 = v^T Ws v  (no pass over N needed)
        float t = 0.f;
#pragma unroll
        for (int k = 0; k < 8; ++k) t = fmaf(row[k], __shfl(v, k, 8), t);
        float s = v * t;
        s += __shfl_xor(s, 1, 8); s += __shfl_xor(s, 2, 8); s += __shfl_xor(s, 4, 8);
        float invn = 1.f / sqrtf(s);
        if (grp == 0) {
            s_vfn[m] = v * invn;
        } else {
            const float* Cr = ws + OFF_WSA + b * 192 + 128;
            float cf = 0.f;
#pragma unroll
            for (int k = 0; k < 8; ++k) cf = fmaf(Cr[m * 8 + k], __shfl(v, k, 8), cf);
            s_coef[m] = cf * invn;
        }
    }
    __syncthreads();
    if (threadIdx.x < 64) {
        float acc = 0.f;
#pragma unroll
        for (int k = 0; k < 8; ++k) acc = fmaf(vw[threadIdx.x * 8 + k], s_coef[k], acc);
        s_w2[threadIdx.x] = acc;
    }
    __syncthreads();

    int n0 = tile * 1024 + threadIdx.x * 4;
    const float inv = 1.f / CNTF;
    const float* st = ws + OFF_STATS;

    float uf0 = 0.f, uf1 = 0.f, uf2 = 0.f, uf3 = 0.f;
#pragma unroll
    for (int m = 0; m < 8; ++m) {
        float mean = st[m] * inv;
        float var  = st[8 + m] * inv - mean * mean;
        float a    = fgam[m] / sqrtf(var + 1e-5f);
        float cc   = fbet[m] - mean * a;
        float vf   = s_vfn[m];
        float4 fv  = *(const float4*)(ws + OFF_FXP + (size_t)(b * 8 + m) * NSP + n0);
        float t0 = fmaf(a, fv.x, cc); t0 = t0 > 0.f ? t0 : 0.f; uf0 = fmaf(vf, t0, uf0);
        float t1 = fmaf(a, fv.y, cc); t1 = t1 > 0.f ? t1 : 0.f; uf1 = fmaf(vf, t1, uf1);
        float t2 = fmaf(a, fv.z, cc); t2 = t2 > 0.f ? t2 : 0.f; uf2 = fmaf(vf, t2, uf2);
        float t3 = fmaf(a, fv.w, cc); t3 = t3 > 0.f ? t3 : 0.f; uf3 = fmaf(vf, t3, uf3);
    }

    const float* xp = x   + (size_t)b * CC * NSP + n0;
    float*       op = out + (size_t)b * CC * NSP + n0;
#pragma unroll 8
    for (int c = 0; c < 64; ++c) {
        float w2c = s_w2[c];
        float bc  = vb[c];
        f32x4 xv = __builtin_nontemporal_load((const f32x4*)(xp + (size_t)c * NSP));
        f32x4 ov;
        ov.x = fmaf(uf0, w2c, xv.x + bc);
        ov.y = fmaf(uf1, w2c, xv.y + bc);
        ov.z = fmaf(uf2, w2c, xv.z + bc);
        ov.w = fmaf(uf3, w2c, xv.w + bc);
        __builtin_nontemporal_store(ov, (f32x4*)(op + (size_t)c * NSP));
    }
}

// ---------------------------------------------------------------------------
extern "C" void kernel_launch(void* const* d_in, const int* in_sizes, int n_in,
                              void* d_out, int out_size, void* d_ws, size_t ws_size,
                              hipStream_t stream) {
    const float* x    = (const float*)d_in[0];
    const float* f_w  = (const float*)d_in[1];
    const float* f_b  = (const float*)d_in[2];
    const float* f_g  = (const float*)d_in[3];
    const float* f_be = (const float*)d_in[4];
    const float* g_w  = (const float*)d_in[5];
    const float* g_b  = (const float*)d_in[6];
    const float* g_g  = (const float*)d_in[7];
    const float* g_be = (const float*)d_in[8];
    const float* h_w  = (const float*)d_in[9];
    const float* h_b  = (const float*)d_in[10];
    const float* v_w  = (const float*)d_in[11];
    const float* v_b  = (const float*)d_in[12];
    const float* v0f  = (const float*)d_in[13];
    const float* v0g  = (const float*)d_in[14];
    float* ws  = (float*)d_ws;
    float* out = (float*)d_out;

    // zero the atomic accumulators (stats + Gram), contiguous region
    (void)hipMemsetAsync(ws + OFF_STATS, 0, (32 + BB * 192) * sizeof(float), stream);

    k_conv<<<512, 256, 0, stream>>>(x, f_w, g_w, h_w, f_b, g_b, h_b, ws);
    k_gram<<<768, 256, 0, stream>>>(f_g, f_be, g_g, g_be, ws);
    k_out <<<512, 256, 0, stream>>>(x, f_g, f_be, v_w, v_b, v0f, v0g, ws, out);
}

// Round 4
// 121.209 us; speedup vs baseline: 1.3130x; 1.0686x over previous
//
#include <hip/hip_runtime.h>

// Problem constants
#define BB   32
#define CC   64
#define MM   8
#define NSP  16384            // H*W = 128*128
#define CNTF 524288.0f        // B*N, BN statistics count

typedef float f32x4 __attribute__((ext_vector_type(4)));

// Workspace layout (float offsets)
#define OFF_FXP   0ll
#define OFF_GXP   (OFF_FXP + (long long)BB*MM*NSP)      //  4,194,304
#define OFF_HX    (OFF_GXP + (long long)BB*MM*NSP)      //  8,388,608
#define OFF_STATS (OFF_HX  + (long long)BB*MM*NSP)      // 12,582,912  [32]: fsum8 fsq8 gsum8 gsq8
#define OFF_WSA   (OFF_STATS + 32)                      // [B][3][64]: Wsf Wsg Cross

// ---------------------------------------------------------------------------
// K1: fused conv + BN-stats. 2 n per thread (float2), 48 accumulator VGPRs
// (no spill), weights via wave-uniform global reads (scalar loads -> SGPRs).
// grid 1024 x 256 -> 4 blocks/CU, 4 waves/SIMD.
__global__ __launch_bounds__(256, 4) void k_conv(const float* __restrict__ x,
        const float* __restrict__ fw, const float* __restrict__ gw,
        const float* __restrict__ hw,
        const float* __restrict__ fb, const float* __restrict__ gb,
        const float* __restrict__ hb, float* __restrict__ ws) {
    __shared__ float sred[4][32];

    int g  = blockIdx.x * 256 + threadIdx.x;   // pair index (2 n per thread)
    int b  = g >> 13;                          // 8192 pairs per batch
    int n0 = (g & 8191) * 2;

    const float* xp = x + (size_t)b * CC * NSP + n0;

    float2 af[8], ag[8], ah[8];
#pragma unroll
    for (int m = 0; m < 8; ++m) {
        af[m].x = af[m].y = fb[m];
        ag[m].x = ag[m].y = gb[m];
        ah[m].x = ah[m].y = hb[m];
    }

#pragma unroll 8
    for (int c = 0; c < 64; ++c) {
        float2 xv = *(const float2*)(xp + (size_t)c * NSP);
#pragma unroll
        for (int m = 0; m < 8; ++m) {
            float wf = fw[m * 64 + c];   // uniform -> s_load
            float wg = gw[m * 64 + c];
            float wh = hw[m * 64 + c];
            af[m].x = fmaf(wf, xv.x, af[m].x); af[m].y = fmaf(wf, xv.y, af[m].y);
            ag[m].x = fmaf(wg, xv.x, ag[m].x); ag[m].y = fmaf(wg, xv.y, ag[m].y);
            ah[m].x = fmaf(wh, xv.x, ah[m].x); ah[m].y = fmaf(wh, xv.y, ah[m].y);
        }
    }

    size_t base = (size_t)b * MM * NSP + n0;
#pragma unroll
    for (int m = 0; m < 8; ++m) {
        *(float2*)(ws + OFF_FXP + base + (size_t)m * NSP) = af[m];
        *(float2*)(ws + OFF_GXP + base + (size_t)m * NSP) = ag[m];
        *(float2*)(ws + OFF_HX  + base + (size_t)m * NSP) = ah[m];
    }

    // BN stats from registers: per-channel sum & sumsq for f and g
    int wid = threadIdx.x >> 6, lane = threadIdx.x & 63;
#pragma unroll
    for (int m = 0; m < 8; ++m) {
        float fs = af[m].x + af[m].y;
        float fq = af[m].x * af[m].x + af[m].y * af[m].y;
        float gs = ag[m].x + ag[m].y;
        float gq = ag[m].x * ag[m].x + ag[m].y * ag[m].y;
#pragma unroll
        for (int o = 1; o < 64; o <<= 1) {
            fs += __shfl_xor(fs, o); fq += __shfl_xor(fq, o);
            gs += __shfl_xor(gs, o); gq += __shfl_xor(gq, o);
        }
        if (lane == 0) {
            sred[wid][m] = fs; sred[wid][8 + m] = fq;
            sred[wid][16 + m] = gs; sred[wid][24 + m] = gq;
        }
    }
    __syncthreads();
    if (threadIdx.x < 32) {
        float t = sred[0][threadIdx.x] + sred[1][threadIdx.x]
                + sred[2][threadIdx.x] + sred[3][threadIdx.x];
        atomicAdd(ws + OFF_STATS + threadIdx.x, t);
    }
}

// ---------------------------------------------------------------------------
// K2: per-batch 8x8 Gram matrices. which: 0=Wsf(fx,fx) 1=Wsg(gx,gx) 2=Cross(hx,gx)
// grid 768 = 32 b * 3 which * 8 chunks; float4 reads (2 per thread per m)
__global__ __launch_bounds__(256) void k_gram(
        const float* __restrict__ fgam, const float* __restrict__ fbet,
        const float* __restrict__ ggam, const float* __restrict__ gbet,
        float* __restrict__ ws) {
    int bid = blockIdx.x;
    int chunk = bid & 7, which = (bid >> 3) % 3, b = bid / 24;

    const float* st  = ws + OFF_STATS + (which == 0 ? 0 : 16);
    const float* gam = (which == 0) ? fgam : ggam;
    const float* bet = (which == 0) ? fbet : gbet;
    const float inv = 1.f / CNTF;
    float a[8], ccf[8];
#pragma unroll
    for (int m = 0; m < 8; ++m) {
        float mean = st[m] * inv;
        float var  = st[8 + m] * inv - mean * mean;
        float sc   = gam[m] / sqrtf(var + 1e-5f);
        a[m] = sc; ccf[m] = bet[m] - mean * sc;
    }

    const float* src  = ws + (which == 0 ? OFF_FXP : OFF_GXP) + (size_t)b * MM * NSP;
    const float* hsrc = ws + OFF_HX + (size_t)b * MM * NSP;

    float acc[64];
#pragma unroll
    for (int j = 0; j < 64; ++j) acc[j] = 0.f;

#pragma unroll
    for (int i = 0; i < 2; ++i) {
        int n = (chunk * 512 + i * 256 + threadIdx.x) * 4;
        float4 vv[8], hh[8];
#pragma unroll
        for (int m = 0; m < 8; ++m) {
            float4 t = *(const float4*)(src + (size_t)m * NSP + n);
            t.x = fmaf(a[m], t.x, ccf[m]); t.x = t.x > 0.f ? t.x : 0.f;
            t.y = fmaf(a[m], t.y, ccf[m]); t.y = t.y > 0.f ? t.y : 0.f;
            t.z = fmaf(a[m], t.z, ccf[m]); t.z = t.z > 0.f ? t.z : 0.f;
            t.w = fmaf(a[m], t.w, ccf[m]); t.w = t.w > 0.f ? t.w : 0.f;
            vv[m] = t;
        }
        if (which == 2) {
#pragma unroll
            for (int m = 0; m < 8; ++m) hh[m] = *(const float4*)(hsrc + (size_t)m * NSP + n);
        } else {
#pragma unroll
            for (int m = 0; m < 8; ++m) hh[m] = vv[m];
        }
#pragma unroll
        for (int m2 = 0; m2 < 8; ++m2)
#pragma unroll
            for (int k = 0; k < 8; ++k) {
                float t = acc[m2 * 8 + k];
                t = fmaf(hh[m2].x, vv[k].x, t);
                t = fmaf(hh[m2].y, vv[k].y, t);
                t = fmaf(hh[m2].z, vv[k].z, t);
                t = fmaf(hh[m2].w, vv[k].w, t);
                acc[m2 * 8 + k] = t;
            }
    }

    // reduce-scatter butterfly across the wave: all register indices static,
    // lane l ends with the total of acc[bitrev6(l)] in acc[0].
    int lane = threadIdx.x & 63;
#pragma unroll
    for (int s2 = 0; s2 < 6; ++s2) {
        int half = 32 >> s2;
        int up = (lane >> s2) & 1;
#pragma unroll
        for (int j = 0; j < 32; ++j) {
            if (j >= half) break;
            float send = up ? acc[j] : acc[j + half];
            float recv = __shfl_xor(send, 1 << s2);
            float keep = up ? acc[j + half] : acc[j];
            acc[j] = keep + recv;
        }
    }
    __shared__ float sacc[64];
    if (threadIdx.x < 64) sacc[threadIdx.x] = 0.f;
    __syncthreads();
    int rev = __brev((unsigned)lane) >> 26;
    atomicAdd(&sacc[rev], acc[0]);
    __syncthreads();
    if (threadIdx.x < 64)
        atomicAdd(ws + OFF_WSA + b * 192 + which * 64 + threadIdx.x, sacc[threadIdx.x]);
}

// ---------------------------------------------------------------------------
// K3: fused power-iteration + rank-1 epilogue + residual.
// grid 1024 = 32 b * 16 n-tiles * 2 c-halves; lanes 0-15 run the 30-iter 8x8
// power iteration, then w2 = v_w @ coef in LDS, then
// out[b,c,n] = uf[n]*w2[c] + v_b[c] + x[b,c,n] for this block's 32 channels.
__global__ __launch_bounds__(256, 4) void k_out(const float* __restrict__ x,
        const float* __restrict__ fgam, const float* __restrict__ fbet,
        const float* __restrict__ vw, const float* __restrict__ vb,
        const float* __restrict__ v0f, const float* __restrict__ v0g,
        const float* __restrict__ ws, float* __restrict__ out) {
    int bid = blockIdx.x;
    int b = bid >> 5, sub = bid & 31;
    int tile = sub & 15, ch0 = (sub >> 4) * 32;
    __shared__ float s_vfn[8], s_coef[8], s_w2[64];

    if (threadIdx.x < 16) {
        int grp = threadIdx.x >> 3, m = threadIdx.x & 7;
        const float* Ws = ws + OFF_WSA + b * 192 + grp * 64;
        float row[8];
#pragma unroll
        for (int k = 0; k < 8; ++k) row[k] = Ws[m * 8 + k];
        float v = (grp == 0 ? v0f : v0g)[b * 8 + m];
        for (int it = 0; it < 30; ++it) {
            float t = 0.f;
#pragma unroll
            for (int k = 0; k < 8; ++k) t = fmaf(row[k], __shfl(v, k, 8), t);
            float s = t * t;
            s += __shfl_xor(s, 1, 8); s += __shfl_xor(s, 2, 8); s += __shfl_xor(s, 4, 8);
            v = t / sqrtf(s);
        }
        // ||W v||^2 = v^T Ws v  (no pass over N needed)
        float t = 0.f;
#pragma unroll
        for (int k = 0; k < 8; ++k) t = fmaf(row[k], __shfl(v, k, 8), t);
        float s = v * t;
        s += __shfl_xor(s, 1, 8); s += __shfl_xor(s, 2, 8); s += __shfl_xor(s, 4, 8);
        float invn = 1.f / sqrtf(s);
        if (grp == 0) {
            s_vfn[m] = v * invn;
        } else {
            const float* Cr = ws + OFF_WSA + b * 192 + 128;
            float cf = 0.f;
#pragma unroll
            for (int k = 0; k < 8; ++k) cf = fmaf(Cr[m * 8 + k], __shfl(v, k, 8), cf);
            s_coef[m] = cf * invn;
        }
    }
    __syncthreads();
    if (threadIdx.x < 64) {
        float acc = 0.f;
#pragma unroll
        for (int k = 0; k < 8; ++k) acc = fmaf(vw[threadIdx.x * 8 + k], s_coef[k], acc);
        s_w2[threadIdx.x] = acc;
    }
    __syncthreads();

    int n0 = tile * 1024 + threadIdx.x * 4;
    const float inv = 1.f / CNTF;
    const float* st = ws + OFF_STATS;

    float uf0 = 0.f, uf1 = 0.f, uf2 = 0.f, uf3 = 0.f;
#pragma unroll
    for (int m = 0; m < 8; ++m) {
        float mean = st[m] * inv;
        float var  = st[8 + m] * inv - mean * mean;
        float a    = fgam[m] / sqrtf(var + 1e-5f);
        float cc   = fbet[m] - mean * a;
        float vf   = s_vfn[m];
        float4 fv  = *(const float4*)(ws + OFF_FXP + (size_t)(b * 8 + m) * NSP + n0);
        float t0 = fmaf(a, fv.x, cc); t0 = t0 > 0.f ? t0 : 0.f; uf0 = fmaf(vf, t0, uf0);
        float t1 = fmaf(a, fv.y, cc); t1 = t1 > 0.f ? t1 : 0.f; uf1 = fmaf(vf, t1, uf1);
        float t2 = fmaf(a, fv.z, cc); t2 = t2 > 0.f ? t2 : 0.f; uf2 = fmaf(vf, t2, uf2);
        float t3 = fmaf(a, fv.w, cc); t3 = t3 > 0.f ? t3 : 0.f; uf3 = fmaf(vf, t3, uf3);
    }

    const float* xp = x   + (size_t)(b * CC + ch0) * NSP + n0;
    float*       op = out + (size_t)(b * CC + ch0) * NSP + n0;
#pragma unroll 8
    for (int c = 0; c < 32; ++c) {
        float w2c = s_w2[ch0 + c];
        float bc  = vb[ch0 + c];
        float4 xv = *(const float4*)(xp + (size_t)c * NSP);   // want the L3 hit
        f32x4 ov;
        ov.x = fmaf(uf0, w2c, xv.x + bc);
        ov.y = fmaf(uf1, w2c, xv.y + bc);
        ov.z = fmaf(uf2, w2c, xv.z + bc);
        ov.w = fmaf(uf3, w2c, xv.w + bc);
        __builtin_nontemporal_store(ov, (f32x4*)(op + (size_t)c * NSP));  // out never re-read
    }
}

// ---------------------------------------------------------------------------
extern "C" void kernel_launch(void* const* d_in, const int* in_sizes, int n_in,
                              void* d_out, int out_size, void* d_ws, size_t ws_size,
                              hipStream_t stream) {
    const float* x    = (const float*)d_in[0];
    const float* f_w  = (const float*)d_in[1];
    const float* f_b  = (const float*)d_in[2];
    const float* f_g  = (const float*)d_in[3];
    const float* f_be = (const float*)d_in[4];
    const float* g_w  = (const float*)d_in[5];
    const float* g_b  = (const float*)d_in[6];
    const float* g_g  = (const float*)d_in[7];
    const float* g_be = (const float*)d_in[8];
    const float* h_w  = (const float*)d_in[9];
    const float* h_b  = (const float*)d_in[10];
    const float* v_w  = (const float*)d_in[11];
    const float* v_b  = (const float*)d_in[12];
    const float* v0f  = (const float*)d_in[13];
    const float* v0g  = (const float*)d_in[14];
    float* ws  = (float*)d_ws;
    float* out = (float*)d_out;

    // zero the atomic accumulators (stats + Gram), contiguous region
    (void)hipMemsetAsync(ws + OFF_STATS, 0, (32 + BB * 192) * sizeof(float), stream);

    k_conv<<<1024, 256, 0, stream>>>(x, f_w, g_w, h_w, f_b, g_b, h_b, ws);
    k_gram<<<768,  256, 0, stream>>>(f_g, f_be, g_g, g_be, ws);
    k_out <<<1024, 256, 0, stream>>>(x, f_g, f_be, v_w, v_b, v0f, v0g, ws, out);
}

// Round 5
// 108.491 us; speedup vs baseline: 1.4669x; 1.1172x over previous
//
#include <hip/hip_runtime.h>

// Problem constants
#define BB   32
#define CC   64
#define MM   8
#define NSP  16384            // H*W = 128*128
#define CNTF 524288.0f        // B*N, BN statistics count

typedef float f32x4 __attribute__((ext_vector_type(4)));

// Workspace layout (float offsets)
#define OFF_FXP   0ll
#define OFF_GXP   (OFF_FXP + (long long)BB*MM*NSP)      //  4,194,304
#define OFF_HX    (OFF_GXP + (long long)BB*MM*NSP)      //  8,388,608
#define OFF_STATS (OFF_HX  + (long long)BB*MM*NSP)      // 12,582,912  [32]: fsum8 fsq8 gsum8 gsq8
#define OFF_WSA   (OFF_STATS + 32)                      // [B][3][64]: Wsf Wsg Cross

#define AXPY(A, WS, XV) \
    (A).x = fmaf((WS), (XV).x, (A).x); (A).y = fmaf((WS), (XV).y, (A).y); \
    (A).z = fmaf((WS), (XV).z, (A).z); (A).w = fmaf((WS), (XV).w, (A).w);

// ---------------------------------------------------------------------------
// K1: fused pack + conv + BN-stats. float4 per thread (16 B/lane), LDS
// weights, launch_bounds(256,2): grid 512 = 2 blocks/CU, VGPR cap 256 so the
// 96-register accumulator set does NOT spill (round-3 failure mode).
__global__ __launch_bounds__(256, 2) void k_conv(const float* __restrict__ x,
        const float* __restrict__ fw, const float* __restrict__ gw,
        const float* __restrict__ hw,
        const float* __restrict__ fb, const float* __restrict__ gb,
        const float* __restrict__ hb, float* __restrict__ ws) {
    __shared__ float wt[1536];          // [c][24]: f0..7 g0..7 h0..7
    __shared__ float sred[4][32];
    for (int i = threadIdx.x; i < 1536; i += 256) {
        int c = i / 24, k = i % 24;
        float v = (k < 8) ? fw[k * 64 + c]
                : (k < 16) ? gw[(k - 8) * 64 + c]
                           : hw[(k - 16) * 64 + c];
        wt[i] = v;
    }
    __syncthreads();

    int g  = blockIdx.x * 256 + threadIdx.x;   // quad index (4 n per thread)
    int b  = g >> 12;                          // 4096 quads per batch
    int n0 = (g & 4095) * 4;

    const float* xp = x + (size_t)b * CC * NSP + n0;

    float4 af[8], ag[8], ah[8];
#pragma unroll
    for (int m = 0; m < 8; ++m) {
        float bf = fb[m], bg = gb[m], bh = hb[m];
        af[m] = make_float4(bf, bf, bf, bf);
        ag[m] = make_float4(bg, bg, bg, bg);
        ah[m] = make_float4(bh, bh, bh, bh);
    }

#pragma unroll 8
    for (int c = 0; c < 64; ++c) {
        float4 xv = *(const float4*)(xp + (size_t)c * NSP);
        const float4* w4 = (const float4*)(&wt[c * 24]);
        float4 wf0 = w4[0], wf1 = w4[1], wg0 = w4[2], wg1 = w4[3], wh0 = w4[4], wh1 = w4[5];
        AXPY(af[0], wf0.x, xv); AXPY(af[1], wf0.y, xv); AXPY(af[2], wf0.z, xv); AXPY(af[3], wf0.w, xv);
        AXPY(af[4], wf1.x, xv); AXPY(af[5], wf1.y, xv); AXPY(af[6], wf1.z, xv); AXPY(af[7], wf1.w, xv);
        AXPY(ag[0], wg0.x, xv); AXPY(ag[1], wg0.y, xv); AXPY(ag[2], wg0.z, xv); AXPY(ag[3], wg0.w, xv);
        AXPY(ag[4], wg1.x, xv); AXPY(ag[5], wg1.y, xv); AXPY(ag[6], wg1.z, xv); AXPY(ag[7], wg1.w, xv);
        AXPY(ah[0], wh0.x, xv); AXPY(ah[1], wh0.y, xv); AXPY(ah[2], wh0.z, xv); AXPY(ah[3], wh0.w, xv);
        AXPY(ah[4], wh1.x, xv); AXPY(ah[5], wh1.y, xv); AXPY(ah[6], wh1.z, xv); AXPY(ah[7], wh1.w, xv);
    }

    size_t base = (size_t)b * MM * NSP + n0;
#pragma unroll
    for (int m = 0; m < 8; ++m) {
        *(float4*)(ws + OFF_FXP + base + (size_t)m * NSP) = af[m];
        *(float4*)(ws + OFF_GXP + base + (size_t)m * NSP) = ag[m];
        *(float4*)(ws + OFF_HX  + base + (size_t)m * NSP) = ah[m];
    }

    // BN stats from registers: per-channel sum & sumsq for f and g
    int wid = threadIdx.x >> 6, lane = threadIdx.x & 63;
#pragma unroll
    for (int m = 0; m < 8; ++m) {
        float fs = af[m].x + af[m].y + af[m].z + af[m].w;
        float fq = af[m].x * af[m].x + af[m].y * af[m].y + af[m].z * af[m].z + af[m].w * af[m].w;
        float gs = ag[m].x + ag[m].y + ag[m].z + ag[m].w;
        float gq = ag[m].x * ag[m].x + ag[m].y * ag[m].y + ag[m].z * ag[m].z + ag[m].w * ag[m].w;
#pragma unroll
        for (int o = 1; o < 64; o <<= 1) {
            fs += __shfl_xor(fs, o); fq += __shfl_xor(fq, o);
            gs += __shfl_xor(gs, o); gq += __shfl_xor(gq, o);
        }
        if (lane == 0) {
            sred[wid][m] = fs; sred[wid][8 + m] = fq;
            sred[wid][16 + m] = gs; sred[wid][24 + m] = gq;
        }
    }
    __syncthreads();
    if (threadIdx.x < 32) {
        float t = sred[0][threadIdx.x] + sred[1][threadIdx.x]
                + sred[2][threadIdx.x] + sred[3][threadIdx.x];
        atomicAdd(ws + OFF_STATS + threadIdx.x, t);
    }
}

// ---------------------------------------------------------------------------
// K2: per-batch 8x8 Gram matrices. which: 0=Wsf(fx,fx) 1=Wsg(gx,gx) 2=Cross(hx,gx)
// grid 768 = 32 b * 3 which * 8 chunks; float4 reads (2 per thread per m)
__global__ __launch_bounds__(256) void k_gram(
        const float* __restrict__ fgam, const float* __restrict__ fbet,
        const float* __restrict__ ggam, const float* __restrict__ gbet,
        float* __restrict__ ws) {
    int bid = blockIdx.x;
    int chunk = bid & 7, which = (bid >> 3) % 3, b = bid / 24;

    const float* st  = ws + OFF_STATS + (which == 0 ? 0 : 16);
    const float* gam = (which == 0) ? fgam : ggam;
    const float* bet = (which == 0) ? fbet : gbet;
    const float inv = 1.f / CNTF;
    float a[8], ccf[8];
#pragma unroll
    for (int m = 0; m < 8; ++m) {
        float mean = st[m] * inv;
        float var  = st[8 + m] * inv - mean * mean;
        float sc   = gam[m] / sqrtf(var + 1e-5f);
        a[m] = sc; ccf[m] = bet[m] - mean * sc;
    }

    const float* src  = ws + (which == 0 ? OFF_FXP : OFF_GXP) + (size_t)b * MM * NSP;
    const float* hsrc = ws + OFF_HX + (size_t)b * MM * NSP;

    float acc[64];
#pragma unroll
    for (int j = 0; j < 64; ++j) acc[j] = 0.f;

#pragma unroll
    for (int i = 0; i < 2; ++i) {
        int n = (chunk * 512 + i * 256 + threadIdx.x) * 4;
        float4 vv[8], hh[8];
#pragma unroll
        for (int m = 0; m < 8; ++m) {
            float4 t = *(const float4*)(src + (size_t)m * NSP + n);
            t.x = fmaf(a[m], t.x, ccf[m]); t.x = t.x > 0.f ? t.x : 0.f;
            t.y = fmaf(a[m], t.y, ccf[m]); t.y = t.y > 0.f ? t.y : 0.f;
            t.z = fmaf(a[m], t.z, ccf[m]); t.z = t.z > 0.f ? t.z : 0.f;
            t.w = fmaf(a[m], t.w, ccf[m]); t.w = t.w > 0.f ? t.w : 0.f;
            vv[m] = t;
        }
        if (which == 2) {
#pragma unroll
            for (int m = 0; m < 8; ++m) hh[m] = *(const float4*)(hsrc + (size_t)m * NSP + n);
        } else {
#pragma unroll
            for (int m = 0; m < 8; ++m) hh[m] = vv[m];
        }
#pragma unroll
        for (int m2 = 0; m2 < 8; ++m2)
#pragma unroll
            for (int k = 0; k < 8; ++k) {
                float t = acc[m2 * 8 + k];
                t = fmaf(hh[m2].x, vv[k].x, t);
                t = fmaf(hh[m2].y, vv[k].y, t);
                t = fmaf(hh[m2].z, vv[k].z, t);
                t = fmaf(hh[m2].w, vv[k].w, t);
                acc[m2 * 8 + k] = t;
            }
    }

    // reduce-scatter butterfly across the wave: all register indices static,
    // lane l ends with the total of acc[bitrev6(l)] in acc[0].
    int lane = threadIdx.x & 63;
#pragma unroll
    for (int s2 = 0; s2 < 6; ++s2) {
        int half = 32 >> s2;
        int up = (lane >> s2) & 1;
#pragma unroll
        for (int j = 0; j < 32; ++j) {
            if (j >= half) break;
            float send = up ? acc[j] : acc[j + half];
            float recv = __shfl_xor(send, 1 << s2);
            float keep = up ? acc[j + half] : acc[j];
            acc[j] = keep + recv;
        }
    }
    __shared__ float sacc[64];
    if (threadIdx.x < 64) sacc[threadIdx.x] = 0.f;
    __syncthreads();
    int rev = __brev((unsigned)lane) >> 26;
    atomicAdd(&sacc[rev], acc[0]);
    __syncthreads();
    if (threadIdx.x < 64)
        atomicAdd(ws + OFF_WSA + b * 192 + which * 64 + threadIdx.x, sacc[threadIdx.x]);
}

// ---------------------------------------------------------------------------
// K3: fused power-iteration + rank-1 epilogue + residual.
// grid 1024 = 32 b * 16 n-tiles * 2 c-halves; lanes 0-15 run the 30-iter 8x8
// power iteration, then w2 = v_w @ coef in LDS, then
// out[b,c,n] = uf[n]*w2[c] + v_b[c] + x[b,c,n] for this block's 32 channels.
__global__ __launch_bounds__(256, 4) void k_out(const float* __restrict__ x,
        const float* __restrict__ fgam, const float* __restrict__ fbet,
        const float* __restrict__ vw, const float* __restrict__ vb,
        const float* __restrict__ v0f, const float* __restrict__ v0g,
        const float* __restrict__ ws, float* __restrict__ out) {
    int bid = blockIdx.x;
    int b = bid >> 5, sub = bid & 31;
    int tile = sub & 15, ch0 = (sub >> 4) * 32;
    __shared__ float s_vfn[8], s_coef[8], s_w2[64];

    if (threadIdx.x < 16) {
        int grp = threadIdx.x >> 3, m = threadIdx.x & 7;
        const float* Ws = ws + OFF_WSA + b * 192 + grp * 64;
        float row[8];
#pragma unroll
        for (int k = 0; k < 8; ++k) row[k] = Ws[m * 8 + k];
        float v = (grp == 0 ? v0f : v0g)[b * 8 + m];
        for (int it = 0; it < 30; ++it) {
            float t = 0.f;
#pragma unroll
            for (int k = 0; k < 8; ++k) t = fmaf(row[k], __shfl(v, k, 8), t);
            float s = t * t;
            s += __shfl_xor(s, 1, 8); s += __shfl_xor(s, 2, 8); s += __shfl_xor(s, 4, 8);
            v = t / sqrtf(s);
        }
        // ||W v||^2 = v^T Ws v  (no pass over N needed)
        float t = 0.f;
#pragma unroll
        for (int k = 0; k < 8; ++k) t = fmaf(row[k], __shfl(v, k, 8), t);
        float s = v * t;
        s += __shfl_xor(s, 1, 8); s += __shfl_xor(s, 2, 8); s += __shfl_xor(s, 4, 8);
        float invn = 1.f / sqrtf(s);
        if (grp == 0) {
            s_vfn[m] = v * invn;
        } else {
            const float* Cr = ws + OFF_WSA + b * 192 + 128;
            float cf = 0.f;
#pragma unroll
            for (int k = 0; k < 8; ++k) cf = fmaf(Cr[m * 8 + k], __shfl(v, k, 8), cf);
            s_coef[m] = cf * invn;
        }
    }
    __syncthreads();
    if (threadIdx.x < 64) {
        float acc = 0.f;
#pragma unroll
        for (int k = 0; k < 8; ++k) acc = fmaf(vw[threadIdx.x * 8 + k], s_coef[k], acc);
        s_w2[threadIdx.x] = acc;
    }
    __syncthreads();

    int n0 = tile * 1024 + threadIdx.x * 4;
    const float inv = 1.f / CNTF;
    const float* st = ws + OFF_STATS;

    float uf0 = 0.f, uf1 = 0.f, uf2 = 0.f, uf3 = 0.f;
#pragma unroll
    for (int m = 0; m < 8; ++m) {
        float mean = st[m] * inv;
        float var  = st[8 + m] * inv - mean * mean;
        float a    = fgam[m] / sqrtf(var + 1e-5f);
        float cc   = fbet[m] - mean * a;
        float vf   = s_vfn[m];
        float4 fv  = *(const float4*)(ws + OFF_FXP + (size_t)(b * 8 + m) * NSP + n0);
        float t0 = fmaf(a, fv.x, cc); t0 = t0 > 0.f ? t0 : 0.f; uf0 = fmaf(vf, t0, uf0);
        float t1 = fmaf(a, fv.y, cc); t1 = t1 > 0.f ? t1 : 0.f; uf1 = fmaf(vf, t1, uf1);
        float t2 = fmaf(a, fv.z, cc); t2 = t2 > 0.f ? t2 : 0.f; uf2 = fmaf(vf, t2, uf2);
        float t3 = fmaf(a, fv.w, cc); t3 = t3 > 0.f ? t3 : 0.f; uf3 = fmaf(vf, t3, uf3);
    }

    const float* xp = x   + (size_t)(b * CC + ch0) * NSP + n0;
    float*       op = out + (size_t)(b * CC + ch0) * NSP + n0;
#pragma unroll 8
    for (int c = 0; c < 32; ++c) {
        float w2c = s_w2[ch0 + c];
        float bc  = vb[ch0 + c];
        float4 xv = *(const float4*)(xp + (size_t)c * NSP);   // want the L3 hit
        f32x4 ov;
        ov.x = fmaf(uf0, w2c, xv.x + bc);
        ov.y = fmaf(uf1, w2c, xv.y + bc);
        ov.z = fmaf(uf2, w2c, xv.z + bc);
        ov.w = fmaf(uf3, w2c, xv.w + bc);
        __builtin_nontemporal_store(ov, (f32x4*)(op + (size_t)c * NSP));  // out never re-read
    }
}

// ---------------------------------------------------------------------------
extern "C" void kernel_launch(void* const* d_in, const int* in_sizes, int n_in,
                              void* d_out, int out_size, void* d_ws, size_t ws_size,
                              hipStream_t stream) {
    const float* x    = (const float*)d_in[0];
    const float* f_w  = (const float*)d_in[1];
    const float* f_b  = (const float*)d_in[2];
    const float* f_g  = (const float*)d_in[3];
    const float* f_be = (const float*)d_in[4];
    const float* g_w  = (const float*)d_in[5];
    const float* g_b  = (const float*)d_in[6];
    const float* g_g  = (const float*)d_in[7];
    const float* g_be = (const float*)d_in[8];
    const float* h_w  = (const float*)d_in[9];
    const float* h_b  = (const float*)d_in[10];
    const float* v_w  = (const float*)d_in[11];
    const float* v_b  = (const float*)d_in[12];
    const float* v0f  = (const float*)d_in[13];
    const float* v0g  = (const float*)d_in[14];
    float* ws  = (float*)d_ws;
    float* out = (float*)d_out;

    // zero the atomic accumulators (stats + Gram), contiguous region
    (void)hipMemsetAsync(ws + OFF_STATS, 0, (32 + BB * 192) * sizeof(float), stream);

    k_conv<<<512,  256, 0, stream>>>(x, f_w, g_w, h_w, f_b, g_b, h_b, ws);
    k_gram<<<768,  256, 0, stream>>>(f_g, f_be, g_g, g_be, ws);
    k_out <<<1024, 256, 0, stream>>>(x, f_g, f_be, v_w, v_b, v0f, v0g, ws, out);
}